// Round 1
// baseline (11384.577 us; speedup 1.0000x reference)
//
#include <hip/hip_runtime.h>

// LSTM persistent-kernel R5 for MI355X (gfx950). B=64,T=512,D=512,U=1024.
// 64 cooperative blocks x 1024 threads (16 waves), each owns 16 hidden
// units (64 gate cols = 4 col-tiles of 16).  Wh slice (K=1024 x 64 cols,
// fp16, B-frag swizzled) lives in LDS (128 KB); Wx slice comes from a
// pre-swizzled fp16 global buffer (4 MB, L2-resident, x-part overlaps the
// barrier wait).  Barrier: per-producer flag stores (64 flags, one lane
// polls one producer) - no atomic-RMW serialization.  h exchange: packed
// 8-B agent-scope bypass stores; consumers use cached vector loads after a
// per-step acquire fence (L1/L2 inv), as in R4.
//
// vs R4 (256 blocks): 4x fewer barrier arrivals/pollers, 4x less LLC
// h-exchange traffic (32 -> 8 MB/step), 4x less fence-refetch traffic.

#define TT 512
#define BB 64
#define DD 512
#define UU 1024
#define G4 4096
#define NBLK 64
#define NTHR 1024
#define NKB_X 16
#define NKB_H 32
#define FLAG_STRIDE 32   // ints; 128 B per flag line

// dynamic LDS: Wh swizzled fp16 [4cg][32kb][512] = 65536 halves = 128 KB
//              gtile [16 waves][256] f32               =  16 KB
// total 147456 B
#define LDS_BYTES 147456

typedef _Float16 f16x8 __attribute__((ext_vector_type(8)));
typedef _Float16 f16x4 __attribute__((ext_vector_type(4)));
typedef float f32x4 __attribute__((ext_vector_type(4)));

__device__ __forceinline__ float sigmoidf_fast(float x) {
  return 1.0f / (1.0f + __expf(-x));
}
__device__ __forceinline__ float tanhf_fast(float x) {
  x = fminf(fmaxf(x, -15.0f), 15.0f);
  float e = __expf(2.0f * x);
  return (e - 1.0f) / (e + 1.0f);
}

__global__ void convert_inputs(const float* __restrict__ x,
                               const float* __restrict__ h0,
                               _Float16* __restrict__ x16,
                               _Float16* __restrict__ h16) {
  int i = blockIdx.x * blockDim.x + threadIdx.x;
  int stride = gridDim.x * blockDim.x;
  const int n4 = BB * TT * DD / 4;
  const float4* x4 = (const float4*)x;
  for (int idx = i; idx < n4; idx += stride) {
    float4 v = x4[idx];
    f16x4 o;
    o[0] = (_Float16)v.x; o[1] = (_Float16)v.y;
    o[2] = (_Float16)v.z; o[3] = (_Float16)v.w;
    *(f16x4*)(x16 + (size_t)idx * 4) = o;
  }
  if (i < BB * UU) h16[i] = (_Float16)h0[i];
}

// Pre-swizzle Wx into per-block B-fragment layout:
// wxs[wg][cg][kb][quad][col][k&7], col = u4*4+gate (16 cols per tile).
__global__ void prep_wx(const float* __restrict__ Wx,
                        _Float16* __restrict__ wxs) {
  const int wg = blockIdx.x;    // 64
  const int tid = threadIdx.x;  // 256
  for (int i = 0; i < 32; ++i) {
    int idx = i * 256 + tid;        // 0..8191 : (cg, k(512), gate)
    int gate = idx & 3;
    int k = (idx >> 2) & 511;
    int cg = idx >> 11;
    const float* src = Wx + (size_t)k * G4 + gate * 1024 + wg * 16 + cg * 4;
    float4 v = *(const float4*)src;
    int base = wg * 32768 + cg * 8192 + (k >> 5) * 512 + ((k >> 3) & 3) * 128 + (k & 7);
    wxs[base + (0 * 4 + gate) * 8] = (_Float16)v.x;
    wxs[base + (1 * 4 + gate) * 8] = (_Float16)v.y;
    wxs[base + (2 * 4 + gate) * 8] = (_Float16)v.z;
    wxs[base + (3 * 4 + gate) * 8] = (_Float16)v.w;
  }
}

__global__ __launch_bounds__(NTHR, 4) void lstm_persistent(
    const _Float16* __restrict__ x16,
    const _Float16* __restrict__ wxs,
    const float* __restrict__ c0,
    const float* __restrict__ Wh,
    const float* __restrict__ b,
    _Float16* __restrict__ h_bufs,      // 2 x [B,U] fp16 ping-pong
    float* __restrict__ out,
    int* __restrict__ flags)            // NBLK spread flag lines
{
  extern __shared__ __align__(16) char smem[];
  _Float16* Blds = (_Float16*)smem;                 // 128 KB
  float* gtile = (float*)(smem + 131072);           // 16 KB

  const int wg   = blockIdx.x;
  const int tid  = threadIdx.x;
  const int wave = tid >> 6;
  const int lane = tid & 63;
  const int quad = lane >> 4;
  const int ncol = lane & 15;
  const int bg   = wave & 3;    // batch group: rows bg*16..bg*16+15
  const int cg   = wave >> 2;   // col tile:   units u0+cg*4..+3 x 4 gates
  const int u0   = wg * 16;

  // ---- stage Wh slice into LDS (fp16, B-fragment swizzle) ----
  for (int i = 0; i < 16; ++i) {
    int idx = i * NTHR + tid;        // 0..16383 : (scg, k(1024), gate)
    int gate = idx & 3;
    int k = (idx >> 2) & 1023;
    int scg = idx >> 12;
    const float* src = Wh + (size_t)k * G4 + gate * 1024 + u0 + scg * 4;
    float4 v = *(const float4*)src;
    int base = scg * 16384 + (k >> 5) * 512 + ((k >> 3) & 3) * 128 + (k & 7);
    Blds[base + (0 * 4 + gate) * 8] = (_Float16)v.x;
    Blds[base + (1 * 4 + gate) * 8] = (_Float16)v.y;
    Blds[base + (2 * 4 + gate) * 8] = (_Float16)v.z;
    Blds[base + (3 * 4 + gate) * 8] = (_Float16)v.w;
  }

  const int gcol = (ncol & 3) * 1024 + u0 + cg * 4 + (ncol >> 2);
  const float bias = b[gcol];

  const int b_idx = bg * 16 + (lane >> 2);
  const int u_idx = u0 + cg * 4 + (lane & 3);
  float c_st = c0[b_idx * UU + u_idx];

  __syncthreads();

  const int arow = bg * 16 + ncol;
  const _Float16* xbase = x16 + (size_t)arow * TT * DD + quad * 8;
  const _Float16* wxb   = wxs + (size_t)wg * 32768 + cg * 8192 + quad * 128 + ncol * 8;
  const _Float16* Bh    = Blds + cg * 16384 + quad * 128 + ncol * 8;
  float* gt = gtile + wave * 256;
  int* myflag = flags + lane * FLAG_STRIDE;   // lane l polls producer l

  for (int t = 0; t < TT; ++t) {
    f32x4 acc  = {bias, bias, bias, bias};
    f32x4 acc2 = {0.f, 0.f, 0.f, 0.f};

    // ---- x-part (no h dependence) : overlaps barrier propagation ----
    const _Float16* xrow = xbase + (size_t)t * DD;
#pragma unroll
    for (int kb = 0; kb < NKB_X; kb += 2) {
      f16x8 a0 = *(const f16x8*)(xrow + kb * 32);
      f16x8 b0 = *(const f16x8*)(wxb + kb * 512);
      acc = __builtin_amdgcn_mfma_f32_16x16x32_f16(a0, b0, acc, 0, 0, 0);
      f16x8 a1 = *(const f16x8*)(xrow + (kb + 1) * 32);
      f16x8 b1 = *(const f16x8*)(wxb + (kb + 1) * 512);
      acc2 = __builtin_amdgcn_mfma_f32_16x16x32_f16(a1, b1, acc2, 0, 0, 0);
    }

    // ---- wait: wave0, lane l spins on producer l's flag (no RMW) ----
    if (t > 0) {
      if (wave == 0) {
        while (__hip_atomic_load(myflag, __ATOMIC_RELAXED,
                                 __HIP_MEMORY_SCOPE_AGENT) < t) {
          __builtin_amdgcn_s_sleep(1);
        }
      }
      if (tid == 0)
        __builtin_amdgcn_fence(__ATOMIC_ACQUIRE, "agent");  // L1/L2 inv
      __syncthreads();
    }

    // ---- h-part : K = 1024 (cached loads; fresh after inv) ----
    const _Float16* hrow =
        h_bufs + (size_t)(t & 1) * BB * UU + (size_t)arow * UU + quad * 8;
#pragma unroll
    for (int kb = 0; kb < NKB_H; kb += 2) {
      f16x8 a0 = *(const f16x8*)(hrow + kb * 32);
      f16x8 b0 = *(const f16x8*)(Bh + kb * 512);
      acc = __builtin_amdgcn_mfma_f32_16x16x32_f16(a0, b0, acc, 0, 0, 0);
      f16x8 a1 = *(const f16x8*)(hrow + (kb + 1) * 32);
      f16x8 b1 = *(const f16x8*)(Bh + (kb + 1) * 512);
      acc2 = __builtin_amdgcn_mfma_f32_16x16x32_f16(a1, b1, acc2, 0, 0, 0);
    }
    acc += acc2;

    // ---- epilogue (per-wave LDS transpose, wave-synchronous) ----
#pragma unroll
    for (int r = 0; r < 4; ++r)
      gt[(quad * 4 + r) * 16 + ncol] = acc[r];
    float4 g4v = *(const float4*)&gt[(lane >> 2) * 16 + (lane & 3) * 4];
    float ig = sigmoidf_fast(g4v.x);
    float fg = sigmoidf_fast(g4v.y);
    float gg = tanhf_fast(g4v.z);
    float og = sigmoidf_fast(g4v.w);
    float cn = fg * c_st + ig * gg;
    c_st = cn;
    float hn = og * tanhf_fast(cn);

    if (t == TT - 1) {
      out[b_idx * UU + u_idx] = hn;
    } else {
      // ---- pack 4 u-values per batch into one 8-B LLC-bypass store ----
      int src = (lane & 15) * 4;
      float v0 = __shfl(hn, src + 0);
      float v1 = __shfl(hn, src + 1);
      float v2 = __shfl(hn, src + 2);
      float v3 = __shfl(hn, src + 3);
      if (lane < 16) {
        union { f16x4 h; unsigned long long u; } cv;
        cv.h[0] = (_Float16)v0; cv.h[1] = (_Float16)v1;
        cv.h[2] = (_Float16)v2; cv.h[3] = (_Float16)v3;
        _Float16* dst = h_bufs + (size_t)((t + 1) & 1) * BB * UU
                        + (size_t)(bg * 16 + lane) * UU + u0 + cg * 4;
        __hip_atomic_store((unsigned long long*)dst, cv.u,
                           __ATOMIC_RELAXED, __HIP_MEMORY_SCOPE_AGENT);
      }
      __syncthreads();   // per-wave vmcnt(0): all h stores globally visible
      if (tid == 0)
        __hip_atomic_store(flags + wg * FLAG_STRIDE, t + 1,
                           __ATOMIC_RELAXED, __HIP_MEMORY_SCOPE_AGENT);
    }
  }
}

extern "C" void kernel_launch(void* const* d_in, const int* in_sizes, int n_in,
                              void* d_out, int out_size, void* d_ws, size_t ws_size,
                              hipStream_t stream) {
  const float* x  = (const float*)d_in[0];
  const float* h0 = (const float*)d_in[1];
  const float* c0 = (const float*)d_in[2];
  const float* Wx = (const float*)d_in[3];
  const float* Wh = (const float*)d_in[4];
  const float* b  = (const float*)d_in[5];
  float* out = (float*)d_out;

  char* ws = (char*)d_ws;
  _Float16* x16  = (_Float16*)ws;                                   // 32 MB
  _Float16* hbuf = (_Float16*)(ws + (size_t)BB * TT * DD * 2);      // 256 KB
  _Float16* wxs  = (_Float16*)(ws + (size_t)BB * TT * DD * 2
                                  + (size_t)2 * BB * UU * 2);       // 4 MB
  int* flags     = (int*)(ws + (size_t)BB * TT * DD * 2
                             + (size_t)2 * BB * UU * 2
                             + (size_t)NBLK * 32768 * 2);           // 8 KB

  hipMemsetAsync(flags, 0, NBLK * FLAG_STRIDE * sizeof(int), stream);
  hipLaunchKernelGGL(convert_inputs, dim3(1024), dim3(256), 0, stream,
                     x, h0, x16, hbuf);
  hipLaunchKernelGGL(prep_wx, dim3(NBLK), dim3(256), 0, stream, Wx, wxs);

  static bool attr_done = false;
  if (!attr_done) {
    (void)hipFuncSetAttribute((const void*)lstm_persistent,
                              hipFuncAttributeMaxDynamicSharedMemorySize,
                              LDS_BYTES);
    attr_done = true;
  }

  static void* args[8];
  args[0] = (void*)&x16;  args[1] = (void*)&wxs;  args[2] = (void*)&c0;
  args[3] = (void*)&Wh;   args[4] = (void*)&b;    args[5] = (void*)&hbuf;
  args[6] = (void*)&out;  args[7] = (void*)&flags;
  hipLaunchCooperativeKernel((void*)lstm_persistent, dim3(NBLK), dim3(NTHR),
                             args, LDS_BYTES, stream);
}

// Round 2
// 3598.067 us; speedup vs baseline: 3.1641x; 3.1641x over previous
//
#include <hip/hip_runtime.h>

// LSTM persistent-kernel R6 for MI355X (gfx950). B=64,T=512,D=512,U=1024.
// Exploits per-batch independence: block (bg,ug) owns 16 batches x 16 units;
// sync + h-exchange only within a bg-group (64 blocks).
// 256 blocks x 512 thr (8 waves, 2/SIMD). Wh (K=1024 x 64 cols, fp16
// B-frag swizzle) in LDS (128 KB); Wx slice pre-swizzled in global (4 MB,
// stays cache-resident: NO per-step fence). Each wave owns a K-slice
// (x:64, h:128) -> h chain = 8 x 8-B device-scope atomic loads/lane;
// partials reduced across waves via LDS. Barrier: per-producer flag lines,
// wave0 lane l polls producer l; producer publishes via one RELEASE store.

#define TT 512
#define BB 64
#define DD 512
#define UU 1024
#define G4 4096
#define NBLK 256
#define NTHR 512
#define FLAG_STRIDE 32            // ints; 128 B per flag line
#define LDS_BYTES 159744          // 128 KB Wh + 28 KB reduce scratch

typedef _Float16 f16x8 __attribute__((ext_vector_type(8)));
typedef _Float16 f16x4 __attribute__((ext_vector_type(4)));
typedef float f32x4 __attribute__((ext_vector_type(4)));
typedef unsigned long long u64_t;

__device__ __forceinline__ float sigmoidf_fast(float x) {
  return 1.0f / (1.0f + __expf(-x));
}
__device__ __forceinline__ float tanhf_fast(float x) {
  x = fminf(fmaxf(x, -15.0f), 15.0f);
  float e = __expf(2.0f * x);
  return (e - 1.0f) / (e + 1.0f);
}

__global__ void convert_inputs(const float* __restrict__ x,
                               const float* __restrict__ h0,
                               _Float16* __restrict__ x16,
                               _Float16* __restrict__ h16) {
  int i = blockIdx.x * blockDim.x + threadIdx.x;
  int stride = gridDim.x * blockDim.x;
  const int n4 = BB * TT * DD / 4;
  const float4* x4 = (const float4*)x;
  for (int idx = i; idx < n4; idx += stride) {
    float4 v = x4[idx];
    f16x4 o;
    o[0] = (_Float16)v.x; o[1] = (_Float16)v.y;
    o[2] = (_Float16)v.z; o[3] = (_Float16)v.w;
    *(f16x4*)(x16 + (size_t)idx * 4) = o;
  }
  if (i < BB * UU) h16[i] = (_Float16)h0[i];
}

// Pre-swizzle Wx into per-unit-slice B-fragment layout:
// wxs[ug][cg][kb16][quad][col16][k&7], units ug*16+cg*4..+4, 16 cols/tile.
__global__ void prep_wx(const float* __restrict__ Wx,
                        _Float16* __restrict__ wxs) {
  const int wg = blockIdx.x;    // 64 unit-slices
  const int tid = threadIdx.x;  // 256
  for (int i = 0; i < 32; ++i) {
    int idx = i * 256 + tid;        // (cg, k(512), gate)
    int gate = idx & 3;
    int k = (idx >> 2) & 511;
    int cg = idx >> 11;
    const float* src = Wx + (size_t)k * G4 + gate * 1024 + wg * 16 + cg * 4;
    float4 v = *(const float4*)src;
    int base = wg * 32768 + cg * 8192 + (k >> 5) * 512 + ((k >> 3) & 3) * 128 + (k & 7);
    wxs[base + (0 * 4 + gate) * 8] = (_Float16)v.x;
    wxs[base + (1 * 4 + gate) * 8] = (_Float16)v.y;
    wxs[base + (2 * 4 + gate) * 8] = (_Float16)v.z;
    wxs[base + (3 * 4 + gate) * 8] = (_Float16)v.w;
  }
}

__global__ __launch_bounds__(NTHR, 2) void lstm_persistent(
    const _Float16* __restrict__ x16,
    const _Float16* __restrict__ wxs,
    const float* __restrict__ c0,
    const float* __restrict__ Wh,
    const float* __restrict__ b,
    _Float16* __restrict__ h_bufs,      // 2 x [B,U] fp16 ping-pong
    float* __restrict__ out,
    int* __restrict__ flags)            // 256 spread flag lines
{
  extern __shared__ __align__(16) char smem[];
  _Float16* Blds = (_Float16*)smem;          // 128 KB: Wh [4ct][32kb][512]
  float* gred = (float*)(smem + 131072);     // 28 KB: 7 slices x [4ct][16][16]

  const int wg   = blockIdx.x;
  const int bg   = wg >> 6;       // batch group: rows bg*16..+16
  const int ug   = wg & 63;       // unit slice: units ug*16..+16
  const int u0   = ug * 16;
  const int tid  = threadIdx.x;
  const int wave = tid >> 6;      // 8 waves = 8 K-slices
  const int lane = tid & 63;
  const int quad = lane >> 4;
  const int ncol = lane & 15;

  // ---- stage Wh slice into LDS (fp16, B-fragment swizzle) ----
  for (int i = 0; i < 32; ++i) {
    int idx = i * NTHR + tid;        // (scg, k(1024), gate)
    int gate = idx & 3;
    int k = (idx >> 2) & 1023;
    int scg = idx >> 12;
    const float* src = Wh + (size_t)k * G4 + gate * 1024 + u0 + scg * 4;
    float4 v = *(const float4*)src;
    int base = scg * 16384 + (k >> 5) * 512 + ((k >> 3) & 3) * 128 + (k & 7);
    Blds[base + (0 * 4 + gate) * 8] = (_Float16)v.x;
    Blds[base + (1 * 4 + gate) * 8] = (_Float16)v.y;
    Blds[base + (2 * 4 + gate) * 8] = (_Float16)v.z;
    Blds[base + (3 * 4 + gate) * 8] = (_Float16)v.w;
  }

  // ---- wave0 per-lane cell state: 4 units x 1 batch per lane ----
  float cstv[4];
  float bias_[4][4];
  int brow = 0, ub = 0;
  if (wave == 0) {
    brow = bg * 16 + (lane >> 2);
    ub   = u0 + (lane & 3) * 4;
    float4 c4 = *(const float4*)(c0 + (size_t)brow * UU + ub);
    cstv[0] = c4.x; cstv[1] = c4.y; cstv[2] = c4.z; cstv[3] = c4.w;
#pragma unroll
    for (int j = 0; j < 4; ++j)
#pragma unroll
      for (int g = 0; g < 4; ++g)
        bias_[j][g] = b[g * 1024 + ub + j];
  }

  __syncthreads();

  const int arow = bg * 16 + ncol;
  const _Float16* xbase = x16 + (size_t)arow * TT * DD + wave * 64 + quad * 8;
  const _Float16* wxw   = wxs + (size_t)ug * 32768 + wave * 1024 + quad * 128 + ncol * 8;
  const _Float16* Bh    = Blds + wave * 2048 + quad * 128 + ncol * 8;
  int* myflag  = flags + (bg * 64 + lane) * FLAG_STRIDE;  // lane l polls producer l
  int* ownflag = flags + (bg * 64 + ug) * FLAG_STRIDE;

  for (int t = 0; t < TT; ++t) {
    f32x4 acc[4];
#pragma unroll
    for (int ct = 0; ct < 4; ++ct) acc[ct] = (f32x4){0.f, 0.f, 0.f, 0.f};

    // ---- x-part, K-slice [wave*64, +64): overlaps the wait ----
    const _Float16* xrow = xbase + (size_t)t * DD;
    f16x8 xa[2];
#pragma unroll
    for (int kb = 0; kb < 2; ++kb) xa[kb] = *(const f16x8*)(xrow + kb * 32);
#pragma unroll
    for (int ct = 0; ct < 4; ++ct)
#pragma unroll
      for (int kb = 0; kb < 2; ++kb)
        acc[ct] = __builtin_amdgcn_mfma_f32_16x16x32_f16(
            xa[kb], *(const f16x8*)(wxw + ct * 8192 + kb * 512), acc[ct], 0, 0, 0);

    // ---- wait: wave0 lane l spins on producer l (64 producers/group) ----
    if (t > 0) {
      if (wave == 0) {
        while (!__all(__hip_atomic_load(myflag, __ATOMIC_RELAXED,
                                        __HIP_MEMORY_SCOPE_AGENT) >= t)) {
        }
      }
      __syncthreads();   // no fence: h is read with device-scope loads
    }

    // ---- h-part, K-slice [wave*128, +128): device-scope bypass loads ----
    const _Float16* hrow = h_bufs + (size_t)(t & 1) * BB * UU
                           + (size_t)arow * UU + wave * 128 + quad * 8;
    u64_t hv[8];
#pragma unroll
    for (int kb = 0; kb < 4; ++kb) {
      hv[2 * kb]     = __hip_atomic_load((u64_t*)(hrow + kb * 32),
                                         __ATOMIC_RELAXED, __HIP_MEMORY_SCOPE_AGENT);
      hv[2 * kb + 1] = __hip_atomic_load((u64_t*)(hrow + kb * 32 + 4),
                                         __ATOMIC_RELAXED, __HIP_MEMORY_SCOPE_AGENT);
    }
    f16x8 hf[4];
#pragma unroll
    for (int kb = 0; kb < 4; ++kb) {
      union { u64_t u[2]; f16x8 v; } cvt;
      cvt.u[0] = hv[2 * kb]; cvt.u[1] = hv[2 * kb + 1];
      hf[kb] = cvt.v;
    }
#pragma unroll
    for (int ct = 0; ct < 4; ++ct)
#pragma unroll
      for (int kb = 0; kb < 4; ++kb)
        acc[ct] = __builtin_amdgcn_mfma_f32_16x16x32_f16(
            hf[kb], *(const f16x8*)(Bh + ct * 16384 + kb * 512), acc[ct], 0, 0, 0);

    // ---- cross-wave K-reduction via LDS ----
    if (wave != 0) {
      float* gs = gred + (wave - 1) * 1024;
#pragma unroll
      for (int ct = 0; ct < 4; ++ct)
#pragma unroll
        for (int r = 0; r < 4; ++r)
          gs[ct * 256 + (quad * 4 + r) * 16 + ncol] = acc[ct][r];
    }
    __syncthreads();

    if (wave == 0) {
#pragma unroll
      for (int w2 = 0; w2 < 7; ++w2)
#pragma unroll
        for (int ct = 0; ct < 4; ++ct)
#pragma unroll
          for (int r = 0; r < 4; ++r)
            acc[ct][r] += gred[w2 * 1024 + ct * 256 + (quad * 4 + r) * 16 + ncol];

      // transpose to [ct][row][col] (wave-synchronous reuse of slice 0)
#pragma unroll
      for (int ct = 0; ct < 4; ++ct)
#pragma unroll
        for (int r = 0; r < 4; ++r)
          gred[ct * 256 + (quad * 4 + r) * 16 + ncol] = acc[ct][r];

      float hn[4];
#pragma unroll
      for (int j = 0; j < 4; ++j) {
        float4 gv = *(const float4*)&gred[(lane & 3) * 256 + (lane >> 2) * 16 + j * 4];
        float ig = sigmoidf_fast(gv.x + bias_[j][0]);
        float fg = sigmoidf_fast(gv.y + bias_[j][1]);
        float gg = tanhf_fast(gv.z + bias_[j][2]);
        float og = sigmoidf_fast(gv.w + bias_[j][3]);
        float cn = fg * cstv[j] + ig * gg;
        cstv[j] = cn;
        hn[j] = og * tanhf_fast(cn);
      }

      if (t == TT - 1) {
        *(float4*)(out + (size_t)brow * UU + ub) =
            make_float4(hn[0], hn[1], hn[2], hn[3]);
      } else {
        union { f16x4 h; u64_t u; } cv;
        cv.h[0] = (_Float16)hn[0]; cv.h[1] = (_Float16)hn[1];
        cv.h[2] = (_Float16)hn[2]; cv.h[3] = (_Float16)hn[3];
        _Float16* dst = h_bufs + (size_t)((t + 1) & 1) * BB * UU
                        + (size_t)brow * UU + ub;
        __hip_atomic_store((u64_t*)dst, cv.u, __ATOMIC_RELAXED,
                           __HIP_MEMORY_SCOPE_AGENT);
        // release: per-wave vmcnt drain orders all 64 lanes' h stores
        if (lane == 0)
          __hip_atomic_store(ownflag, t + 1, __ATOMIC_RELEASE,
                             __HIP_MEMORY_SCOPE_AGENT);
      }
    }
  }
}

extern "C" void kernel_launch(void* const* d_in, const int* in_sizes, int n_in,
                              void* d_out, int out_size, void* d_ws, size_t ws_size,
                              hipStream_t stream) {
  const float* x  = (const float*)d_in[0];
  const float* h0 = (const float*)d_in[1];
  const float* c0 = (const float*)d_in[2];
  const float* Wx = (const float*)d_in[3];
  const float* Wh = (const float*)d_in[4];
  const float* b  = (const float*)d_in[5];
  float* out = (float*)d_out;

  char* ws = (char*)d_ws;
  _Float16* x16  = (_Float16*)ws;                                   // 32 MB
  _Float16* hbuf = (_Float16*)(ws + (size_t)BB * TT * DD * 2);      // 256 KB
  _Float16* wxs  = (_Float16*)(ws + (size_t)BB * TT * DD * 2
                                  + (size_t)2 * BB * UU * 2);       // 4 MB
  int* flags     = (int*)(ws + (size_t)BB * TT * DD * 2
                             + (size_t)2 * BB * UU * 2
                             + (size_t)64 * 32768 * 2);             // 32 KB

  hipMemsetAsync(flags, 0, NBLK * FLAG_STRIDE * sizeof(int), stream);
  hipLaunchKernelGGL(convert_inputs, dim3(1024), dim3(256), 0, stream,
                     x, h0, x16, hbuf);
  hipLaunchKernelGGL(prep_wx, dim3(64), dim3(256), 0, stream, Wx, wxs);

  static bool attr_done = false;
  if (!attr_done) {
    (void)hipFuncSetAttribute((const void*)lstm_persistent,
                              hipFuncAttributeMaxDynamicSharedMemorySize,
                              LDS_BYTES);
    attr_done = true;
  }

  static void* args[8];
  args[0] = (void*)&x16;  args[1] = (void*)&wxs;  args[2] = (void*)&c0;
  args[3] = (void*)&Wh;   args[4] = (void*)&b;    args[5] = (void*)&hbuf;
  args[6] = (void*)&out;  args[7] = (void*)&flags;
  hipLaunchCooperativeKernel((void*)lstm_persistent, dim3(NBLK), dim3(NTHR),
                             args, LDS_BYTES, stream);
}

// Round 3
// 3416.352 us; speedup vs baseline: 3.3324x; 1.0532x over previous
//
#include <hip/hip_runtime.h>

// LSTM persistent-kernel R7 for MI355X (gfx950). B=64,T=512,D=512,U=1024.
// Flagless sentinel handoff: h chunks are 8-B relaxed agent stores; consumers
// spin-load the DATA until != NaN-sentinel (detection == data arrival, ~1 RT).
// No vmcnt drain, no flag store, no acquire fence. h_bufs rotate depth-4;
// wave 4 re-poisons the (t-1)-buffer each step (provably ordered via the
// spin's vmcnt drain + syncthreads before the next publish).
// 256 blocks (bg=4 x ug=64) x 512 thr. Wave = (ct-pair, K-quarter):
// 4 partials/gate, distributed 256-thread epilogue (8 x b128 LDS reads).
// Wh (K=1024 x 64 cols fp16 B-frag swizzle) in LDS 128 KB; Wx pre-swizzled
// in global (4 MB, L2-resident); x-part overlaps the spin window.

#define TT 512
#define BB 64
#define DD 512
#define UU 1024
#define G4 4096
#define NBLK 256
#define NTHR 512
#define SENT 0x7E007E007E007E00ULL   // 4 x fp16 qNaN: real h is never NaN
#define LDS_BYTES 148480             // 128 KB Wh + 17 KB gred (padded)

typedef _Float16 f16x8 __attribute__((ext_vector_type(8)));
typedef _Float16 f16x4 __attribute__((ext_vector_type(4)));
typedef float f32x4 __attribute__((ext_vector_type(4)));
typedef unsigned long long u64_t;

__device__ __forceinline__ float sigmoidf_fast(float x) {
  return 1.0f / (1.0f + __expf(-x));
}
__device__ __forceinline__ float tanhf_fast(float x) {
  x = fminf(fmaxf(x, -15.0f), 15.0f);
  float e = __expf(2.0f * x);
  return (e - 1.0f) / (e + 1.0f);
}

__global__ void convert_inputs(const float* __restrict__ x,
                               const float* __restrict__ h0,
                               _Float16* __restrict__ x16,
                               _Float16* __restrict__ hbufs) {
  int i = blockIdx.x * blockDim.x + threadIdx.x;
  int stride = gridDim.x * blockDim.x;
  const int n4 = BB * TT * DD / 4;
  const float4* x4 = (const float4*)x;
  for (int idx = i; idx < n4; idx += stride) {
    float4 v = x4[idx];
    f16x4 o;
    o[0] = (_Float16)v.x; o[1] = (_Float16)v.y;
    o[2] = (_Float16)v.z; o[3] = (_Float16)v.w;
    *(f16x4*)(x16 + (size_t)idx * 4) = o;
  }
  if (i < BB * UU) hbufs[i] = (_Float16)h0[i];     // buf0 = h(0)
  // poison buffers 1..3 (depth-4 rotation)
  u64_t* pz = (u64_t*)(hbufs + BB * UU);
  const int npz = 3 * BB * UU / 4;
  for (int c = i; c < npz; c += stride) pz[c] = SENT;
}

// Pre-swizzle Wx into per-unit-slice B-fragment layout:
// wxs[ug][cg][kb16][quad][col16][k&7], units ug*16+cg*4..+4, 16 cols/tile.
__global__ void prep_wx(const float* __restrict__ Wx,
                        _Float16* __restrict__ wxs) {
  const int wg = blockIdx.x;    // 64 unit-slices
  const int tid = threadIdx.x;  // 256
  for (int i = 0; i < 32; ++i) {
    int idx = i * 256 + tid;        // (cg, k(512), gate)
    int gate = idx & 3;
    int k = (idx >> 2) & 511;
    int cg = idx >> 11;
    const float* src = Wx + (size_t)k * G4 + gate * 1024 + wg * 16 + cg * 4;
    float4 v = *(const float4*)src;
    int base = wg * 32768 + cg * 8192 + (k >> 5) * 512 + ((k >> 3) & 3) * 128 + (k & 7);
    wxs[base + (0 * 4 + gate) * 8] = (_Float16)v.x;
    wxs[base + (1 * 4 + gate) * 8] = (_Float16)v.y;
    wxs[base + (2 * 4 + gate) * 8] = (_Float16)v.z;
    wxs[base + (3 * 4 + gate) * 8] = (_Float16)v.w;
  }
}

__global__ __launch_bounds__(NTHR, 1) void lstm_persistent(
    const _Float16* __restrict__ x16,
    const _Float16* __restrict__ wxs,
    const float* __restrict__ c0,
    const float* __restrict__ Wh,
    const float* __restrict__ b,
    _Float16* __restrict__ h_bufs,      // 4 x [B,U] fp16 rotation
    float* __restrict__ out)
{
  extern __shared__ __align__(16) char smem[];
  _Float16* Blds = (_Float16*)smem;           // 128 KB: Wh [4ct][32kb][512]
  float* gred = (float*)(smem + 131072);      // [4kh][4ct pad-272][16][16] f32

  const int wg   = blockIdx.x;
  const int bg   = wg >> 6;       // batch group: rows bg*16..+16
  const int ug   = wg & 63;       // unit slice: units ug*16..+16
  const int u0   = ug * 16;
  const int tid  = threadIdx.x;
  const int wave = tid >> 6;
  const int lane = tid & 63;
  const int quad = lane >> 4;
  const int ncol = lane & 15;
  const int cth  = wave & 1;      // ct tiles {cth*2, cth*2+1}
  const int kh   = wave >> 1;     // K quarter

  // ---- stage Wh slice into LDS (fp16, B-fragment swizzle) ----
  for (int i = 0; i < 32; ++i) {
    int idx = i * NTHR + tid;        // (scg, k(1024), gate)
    int gate = idx & 3;
    int k = (idx >> 2) & 1023;
    int scg = idx >> 12;
    const float* src = Wh + (size_t)k * G4 + gate * 1024 + u0 + scg * 4;
    float4 v = *(const float4*)src;
    int base = scg * 16384 + (k >> 5) * 512 + ((k >> 3) & 3) * 128 + (k & 7);
    Blds[base + (0 * 4 + gate) * 8] = (_Float16)v.x;
    Blds[base + (1 * 4 + gate) * 8] = (_Float16)v.y;
    Blds[base + (2 * 4 + gate) * 8] = (_Float16)v.z;
    Blds[base + (3 * 4 + gate) * 8] = (_Float16)v.w;
  }

  // ---- epilogue thread state: cell (erow, u0+eucol), tid < 256 ----
  const int erow  = tid >> 4;
  const int eucol = tid & 15;
  float c_st = 0.f;
  float bias_[4];
  if (tid < 256) {
    c_st = c0[(size_t)(bg * 16 + erow) * UU + u0 + eucol];
#pragma unroll
    for (int g = 0; g < 4; ++g) bias_[g] = b[g * 1024 + u0 + eucol];
  }

  __syncthreads();

  const int arow = bg * 16 + ncol;
  const _Float16* xbase = x16 + (size_t)arow * TT * DD + kh * 128 + quad * 8;
  const _Float16* wxb   = wxs + (size_t)ug * 32768 + (kh * 4) * 512
                          + quad * 128 + ncol * 8;
  const _Float16* Bh    = Blds + quad * 128 + ncol * 8;
  const int ct0 = cth * 2, ct1 = cth * 2 + 1;

  for (int t = 0; t < TT; ++t) {
    f32x4 acc0 = {0.f, 0.f, 0.f, 0.f};
    f32x4 acc1 = {0.f, 0.f, 0.f, 0.f};

    // ---- x-part, K-slice [kh*128, +128): overlaps the handoff window ----
    const _Float16* xrow = xbase + (size_t)t * DD;
#pragma unroll
    for (int kb = 0; kb < 4; ++kb) {
      f16x8 a = *(const f16x8*)(xrow + kb * 32);
      acc0 = __builtin_amdgcn_mfma_f32_16x16x32_f16(
          a, *(const f16x8*)(wxb + ct0 * 8192 + kb * 512), acc0, 0, 0, 0);
      acc1 = __builtin_amdgcn_mfma_f32_16x16x32_f16(
          a, *(const f16x8*)(wxb + ct1 * 8192 + kb * 512), acc1, 0, 0, 0);
    }

    // ---- h-part spin: data IS the flag (sentinel = fp16 NaN x4) ----
    const u64_t* hp = (const u64_t*)(h_bufs + (size_t)(t & 3) * BB * UU
                                     + (size_t)arow * UU + kh * 256 + quad * 8);
    u64_t hv[16];
    for (;;) {
      bool ok = true;
#pragma unroll
      for (int kb = 0; kb < 8; ++kb) {
        hv[2 * kb]     = __hip_atomic_load(hp + kb * 8, __ATOMIC_RELAXED,
                                           __HIP_MEMORY_SCOPE_AGENT);
        hv[2 * kb + 1] = __hip_atomic_load(hp + kb * 8 + 1, __ATOMIC_RELAXED,
                                           __HIP_MEMORY_SCOPE_AGENT);
      }
#pragma unroll
      for (int c = 0; c < 16; ++c) ok &= (hv[c] != SENT);
      if (__all(ok)) break;
    }

    // ---- h-part MFMAs, K-slice [kh*256, +256) ----
#pragma unroll
    for (int kb = 0; kb < 8; ++kb) {
      union { u64_t u[2]; f16x8 v; } cv;
      cv.u[0] = hv[2 * kb]; cv.u[1] = hv[2 * kb + 1];
      const int kg = kh * 8 + kb;
      acc0 = __builtin_amdgcn_mfma_f32_16x16x32_f16(
          cv.v, *(const f16x8*)(Bh + ct0 * 16384 + kg * 512), acc0, 0, 0, 0);
      acc1 = __builtin_amdgcn_mfma_f32_16x16x32_f16(
          cv.v, *(const f16x8*)(Bh + ct1 * 16384 + kg * 512), acc1, 0, 0, 0);
    }

    // ---- partials to LDS: [kh][ct(272 pad)][row16][col16] ----
#pragma unroll
    for (int r = 0; r < 4; ++r) {
      gred[kh * 1088 + ct0 * 272 + (quad * 4 + r) * 16 + ncol] = acc0[r];
      gred[kh * 1088 + ct1 * 272 + (quad * 4 + r) * 16 + ncol] = acc1[r];
    }
    __syncthreads();

    if (tid < 256) {
      // ---- distributed epilogue: 1 cell/thread, 4 b128 reads ----
      float4 s = make_float4(0.f, 0.f, 0.f, 0.f);
#pragma unroll
      for (int k2 = 0; k2 < 4; ++k2) {
        const float4 p = *(const float4*)&gred[k2 * 1088 + (eucol >> 2) * 272
                                               + erow * 16 + (eucol & 3) * 4];
        s.x += p.x; s.y += p.y; s.z += p.z; s.w += p.w;
      }
      float ig = sigmoidf_fast(s.x + bias_[0]);
      float fg = sigmoidf_fast(s.y + bias_[1]);
      float gg = tanhf_fast(s.z + bias_[2]);
      float og = sigmoidf_fast(s.w + bias_[3]);
      float cn = fg * c_st + ig * gg;
      c_st = cn;
      float hn = og * tanhf_fast(cn);

      if (t == TT - 1) {
        out[(size_t)(bg * 16 + erow) * UU + u0 + eucol] = hn;
      } else {
        // pack 4 u-values/batch into one 8-B store (waves 0-3, lane<16)
        int src = (lane >> 2) * 16 + (lane & 3) * 4;
        float v0 = __shfl(hn, src + 0);
        float v1 = __shfl(hn, src + 1);
        float v2 = __shfl(hn, src + 2);
        float v3 = __shfl(hn, src + 3);
        if (lane < 16) {
          union { f16x4 h; u64_t u; } cv;
          cv.h[0] = (_Float16)v0; cv.h[1] = (_Float16)v1;
          cv.h[2] = (_Float16)v2; cv.h[3] = (_Float16)v3;
          int rowp = wave * 4 + (lane >> 2);
          _Float16* dst = h_bufs + (size_t)((t + 1) & 3) * BB * UU
                          + (size_t)(bg * 16 + rowp) * UU + u0 + (lane & 3) * 4;
          __hip_atomic_store((u64_t*)dst, cv.u, __ATOMIC_RELAXED,
                             __HIP_MEMORY_SCOPE_AGENT);
        }
      }
    } else if (wave == 4) {
      // ---- re-poison own region of buf[(t-1)&3] (safe: depth-4) ----
      u64_t* pz = (u64_t*)(h_bufs + (size_t)((t - 1) & 3) * BB * UU
                           + (size_t)(bg * 16 + (lane >> 2)) * UU
                           + u0 + (lane & 3) * 4);
      __hip_atomic_store(pz, SENT, __ATOMIC_RELAXED, __HIP_MEMORY_SCOPE_AGENT);
    }
    __syncthreads();   // gred reuse fence (next step's partial writes)
  }
}

extern "C" void kernel_launch(void* const* d_in, const int* in_sizes, int n_in,
                              void* d_out, int out_size, void* d_ws, size_t ws_size,
                              hipStream_t stream) {
  const float* x  = (const float*)d_in[0];
  const float* h0 = (const float*)d_in[1];
  const float* c0 = (const float*)d_in[2];
  const float* Wx = (const float*)d_in[3];
  const float* Wh = (const float*)d_in[4];
  const float* b  = (const float*)d_in[5];
  float* out = (float*)d_out;

  char* ws = (char*)d_ws;
  _Float16* x16  = (_Float16*)ws;                                   // 32 MB
  _Float16* hbuf = (_Float16*)(ws + (size_t)BB * TT * DD * 2);      // 512 KB (4 bufs)
  _Float16* wxs  = (_Float16*)(ws + (size_t)BB * TT * DD * 2
                                  + (size_t)4 * BB * UU * 2);       // 4 MB

  hipLaunchKernelGGL(convert_inputs, dim3(1024), dim3(256), 0, stream,
                     x, h0, x16, hbuf);
  hipLaunchKernelGGL(prep_wx, dim3(64), dim3(256), 0, stream, Wx, wxs);

  static bool attr_done = false;
  if (!attr_done) {
    (void)hipFuncSetAttribute((const void*)lstm_persistent,
                              hipFuncAttributeMaxDynamicSharedMemorySize,
                              LDS_BYTES);
    attr_done = true;
  }

  static void* args[7];
  args[0] = (void*)&x16;  args[1] = (void*)&wxs;  args[2] = (void*)&c0;
  args[3] = (void*)&Wh;   args[4] = (void*)&b;    args[5] = (void*)&hbuf;
  args[6] = (void*)&out;
  hipLaunchCooperativeKernel((void*)lstm_persistent, dim3(NBLK), dim3(NTHR),
                             args, LDS_BYTES, stream);
}